// Round 2
// baseline (35755.130 us; speedup 1.0000x reference)
//
#include <hip/hip_runtime.h>
#include <math.h>

#define T_STEPS 512
#define BSZ     64
#define EDIM    512
#define HDIM    1024
#define KDIM    1536   // E+H
#define N4      4096   // 4*H
#define KSLICES 4
#define KPER    384    // KDIM/KSLICES
#define KT      128    // LDS k-tile
#define LDS_PAD 130    // 128 + 2 (bank spread, keeps 8B alignment)

__global__ __launch_bounds__(256) void zero_kernel(float* p, int n) {
    int i = blockIdx.x * 256 + threadIdx.x;
    if (i < n) p[i] = 0.0f;
}

// z_part[ks][b][n] = sum_{k in slice ks} inp[b][k] * W[k][n]
// inp[b][k] = k < E ? x[t][b][k] : h[b][k-E]
__global__ __launch_bounds__(256) void gemm_step(
    const float* __restrict__ x,    // [T,B,E]
    const float* __restrict__ hbuf, // [B,H]
    const float* __restrict__ Wi, const float* __restrict__ Wo,
    const float* __restrict__ Wf, const float* __restrict__ Wm,
    float* __restrict__ z_part,     // [KSLICES][B][N4]
    int t)
{
    __shared__ float lds[BSZ * LDS_PAD];

    const int tid = threadIdx.x;
    const int n0  = blockIdx.x * 64;      // 64 output cols per block
    const int ks  = blockIdx.y;           // k-slice
    const int n4  = tid & 15;             // 16 col-quads
    const int bq  = tid >> 4;             // 16 row-quads
    const int nl  = 4 * n4;
    const int b0  = 4 * bq;

    const int g = n0 >> 10;               // which gate weight
    const float* W = (g == 0) ? Wi : (g == 1) ? Wo : (g == 2) ? Wf : Wm;
    const int ncol = (n0 & 1023) + nl;    // column within gate weight [K,1024]

    float acc[4][4];
    #pragma unroll
    for (int j = 0; j < 4; ++j)
        #pragma unroll
        for (int i = 0; i < 4; ++i) acc[j][i] = 0.0f;

    const float* xrow = x + (size_t)t * BSZ * EDIM;

    for (int kt = 0; kt < KPER; kt += KT) {
        const int kbase = ks * KPER + kt;
        // cooperative stage of inp[0:64][kbase:kbase+128] into LDS
        #pragma unroll
        for (int i = 0; i < (BSZ * KT) / 256; ++i) {
            int idx = tid + 256 * i;
            int b   = idx >> 7;       // /KT
            int kk  = idx & (KT - 1);
            int kg  = kbase + kk;
            float v = (kg < EDIM) ? xrow[b * EDIM + kg]
                                  : hbuf[b * HDIM + (kg - EDIM)];
            lds[b * LDS_PAD + kk] = v;
        }
        __syncthreads();

        for (int kk = 0; kk < KT; kk += 2) {
            const int kg = kbase + kk;
            float4 w0 = *reinterpret_cast<const float4*>(&W[(size_t)kg * HDIM + ncol]);
            float4 w1 = *reinterpret_cast<const float4*>(&W[(size_t)(kg + 1) * HDIM + ncol]);
            #pragma unroll
            for (int j = 0; j < 4; ++j) {
                float2 a = *reinterpret_cast<const float2*>(&lds[(b0 + j) * LDS_PAD + kk]);
                acc[j][0] += a.x * w0.x; acc[j][1] += a.x * w0.y;
                acc[j][2] += a.x * w0.z; acc[j][3] += a.x * w0.w;
                acc[j][0] += a.y * w1.x; acc[j][1] += a.y * w1.y;
                acc[j][2] += a.y * w1.z; acc[j][3] += a.y * w1.w;
            }
        }
        __syncthreads();
    }

    #pragma unroll
    for (int j = 0; j < 4; ++j) {
        float4 v = make_float4(acc[j][0], acc[j][1], acc[j][2], acc[j][3]);
        *reinterpret_cast<float4*>(
            &z_part[((size_t)ks * BSZ + (b0 + j)) * N4 + n0 + nl]) = v;
    }
}

__global__ __launch_bounds__(256) void gates_step(
    const float* __restrict__ z_part,  // [KSLICES][B][N4]
    const float* __restrict__ bi, const float* __restrict__ bo,
    const float* __restrict__ bf_, const float* __restrict__ bm,
    float* __restrict__ hbuf,          // [B,H]
    float* __restrict__ cbuf,          // [B,H]
    float* __restrict__ out,           // [B,T,H]
    int t)
{
    const int idx = blockIdx.x * 256 + threadIdx.x;  // 65536 = B*H
    const int b   = idx >> 10;
    const int hh  = idx & 1023;

    float zi = bi[hh], zo = bo[hh], zf = bf_[hh], zm = bm[hh];
    #pragma unroll
    for (int s = 0; s < 4; ++s) {
        const float* zp = z_part + ((size_t)s * BSZ + b) * N4;
        zi += zp[hh];
        zo += zp[1024 + hh];
        zf += zp[2048 + hh];
        zm += zp[3072 + hh];
    }

    float ig = 1.0f / (1.0f + expf(-zi));
    float og = 1.0f / (1.0f + expf(-zo));
    float fg = 1.0f / (1.0f + expf(-zf));
    float mg = tanhf(zm);

    float c_old = cbuf[idx];
    float c_new = fg * c_old + ig * mg;
    float h_new = og * tanhf(c_new);

    cbuf[idx] = c_new;
    hbuf[idx] = h_new;
    out[((size_t)b * T_STEPS + t) * HDIM + hh] = h_new;
}

extern "C" void kernel_launch(void* const* d_in, const int* in_sizes, int n_in,
                              void* d_out, int out_size, void* d_ws, size_t ws_size,
                              hipStream_t stream) {
    const float* x   = (const float*)d_in[0];
    const float* Wi  = (const float*)d_in[1];
    const float* bi  = (const float*)d_in[2];
    const float* Wo  = (const float*)d_in[3];
    const float* bo  = (const float*)d_in[4];
    const float* Wf  = (const float*)d_in[5];
    const float* bff = (const float*)d_in[6];
    const float* Wm  = (const float*)d_in[7];
    const float* bm  = (const float*)d_in[8];
    float* out = (float*)d_out;

    float* hbuf  = (float*)d_ws;                 // [B,H]
    float* cbuf  = hbuf + BSZ * HDIM;            // [B,H]
    float* zpart = cbuf + BSZ * HDIM;            // [KSLICES,B,N4]

    // h0 = c0 = 0 (ws is poisoned 0xAA before every call)
    zero_kernel<<<dim3((2 * BSZ * HDIM + 255) / 256), 256, 0, stream>>>(
        hbuf, 2 * BSZ * HDIM);

    for (int t = 0; t < T_STEPS; ++t) {
        gemm_step<<<dim3(64, KSLICES), 256, 0, stream>>>(
            x, hbuf, Wi, Wo, Wf, Wm, zpart, t);
        gates_step<<<dim3((BSZ * HDIM) / 256), 256, 0, stream>>>(
            zpart, bi, bo, bff, bm, hbuf, cbuf, out, t);
    }
}

// Round 3
// 31852.655 us; speedup vs baseline: 1.1225x; 1.1225x over previous
//
#include <hip/hip_runtime.h>
#include <math.h>

#define T_STEPS 512
#define BSZ     64
#define EDIM    512
#define HDIM    1024
#define KDIM    1536   // E+H
#define KS      4      // K slices across blocks
#define KPER    384    // KDIM/KS
#define N4      4096

typedef __bf16 bf16x8 __attribute__((ext_vector_type(8)));
typedef float  f32x4  __attribute__((ext_vector_type(4)));
typedef unsigned short ushort8 __attribute__((ext_vector_type(8)));
typedef unsigned int uint;

// ---------- helpers ----------
__device__ __forceinline__ unsigned short bf16_rne_bits(float f) {
    uint u = __float_as_uint(f);
    return (unsigned short)((u + 0x7fffu + ((u >> 16) & 1u)) >> 16);
}
__device__ __forceinline__ float bf16_bits_to_f32(unsigned short s) {
    return __uint_as_float(((uint)s) << 16);
}

// ================= prep kernels (once per call) =================

__global__ __launch_bounds__(256) void init_state(
    float* __restrict__ cbuf, __bf16* __restrict__ h_hi,
    __bf16* __restrict__ h_lo, uint* __restrict__ cnt)
{
    int i = blockIdx.x * 256 + threadIdx.x;
    if (i < BSZ * HDIM) {
        cbuf[i] = 0.0f;
        h_hi[i] = __builtin_bit_cast(__bf16, (unsigned short)0);
        h_lo[i] = __builtin_bit_cast(__bf16, (unsigned short)0);
    }
    if (i < 64) cnt[i] = 0u;
}

// Wt[n][k] = W_g[k][c], n = g*1024 + c ; split into hi/lo bf16
__global__ __launch_bounds__(256) void prep_w(
    const float* __restrict__ Wi, const float* __restrict__ Wo,
    const float* __restrict__ Wf, const float* __restrict__ Wm,
    __bf16* __restrict__ Wt_hi, __bf16* __restrict__ Wt_lo)
{
    __shared__ float tile[32][33];
    const int g  = blockIdx.z;
    const float* W = (g == 0) ? Wi : (g == 1) ? Wo : (g == 2) ? Wf : Wm;
    const int k0 = blockIdx.x * 32, c0 = blockIdx.y * 32;
    const int tx = threadIdx.x & 31, ty = threadIdx.x >> 5;   // 32 x 8
    #pragma unroll
    for (int j = 0; j < 4; ++j)
        tile[ty + 8 * j][tx] = W[(size_t)(k0 + ty + 8 * j) * HDIM + c0 + tx];
    __syncthreads();
    #pragma unroll
    for (int j = 0; j < 4; ++j) {
        const int n = g * HDIM + c0 + ty + 8 * j;
        float v = tile[tx][ty + 8 * j];
        unsigned short rh = bf16_rne_bits(v);
        float lo = v - bf16_bits_to_f32(rh);
        unsigned short rl = bf16_rne_bits(lo);
        Wt_hi[(size_t)n * KDIM + k0 + tx] = __builtin_bit_cast(__bf16, rh);
        Wt_lo[(size_t)n * KDIM + k0 + tx] = __builtin_bit_cast(__bf16, rl);
    }
}

// ================= per-step fused kernel =================
// grid (64, KS): bx = 16-h-col tile, ks = K slice.
// Block: 256 thr = 4 waves. Wave tile: 32 rows x 32 cols (2 mt x 2 gates).
// LDS A layout: [ch 0..47][b 0..63][8 bf16], ch*8 = k offset in slice.
__global__ __launch_bounds__(256) void step_kernel(
    const float* __restrict__ x,         // [T,B,E]
    const __bf16* __restrict__ Wt_hi,    // [4096][1536]
    const __bf16* __restrict__ Wt_lo,
    const float* __restrict__ bi, const float* __restrict__ bo,
    const float* __restrict__ bfp, const float* __restrict__ bm,
    __bf16* __restrict__ h_hi, __bf16* __restrict__ h_lo,  // [B,H]
    float* __restrict__ cbuf,            // [B,H]
    float* __restrict__ zpart,           // [KS][64][64][64]
    uint* __restrict__ cnt,              // [64]
    float* __restrict__ out,             // [B,T,H]
    int t)
{
    __shared__ __bf16 Ah[48 * 64 * 8];
    __shared__ __bf16 Al[48 * 64 * 8];
    __shared__ uint winner_flag;

    const int tid = threadIdx.x;
    const int bx  = blockIdx.x;
    const int ks  = blockIdx.y;

    // ---- stage A (x | h) hi/lo into LDS ----
    {
        const int b   = tid >> 2;
        const int ch4 = tid & 3;
        const float*  xrow = x + ((size_t)t * BSZ + b) * EDIM;
        const __bf16* hh   = h_hi + b * HDIM;
        const __bf16* hl   = h_lo + b * HDIM;
        #pragma unroll
        for (int i = 0; i < 12; ++i) {
            const int ch = ch4 + 4 * i;
            const int kg = ks * KPER + ch * 8;
            bf16x8 vh, vl;
            if (kg < EDIM) {
                float4 f0 = *reinterpret_cast<const float4*>(&xrow[kg]);
                float4 f1 = *reinterpret_cast<const float4*>(&xrow[kg + 4]);
                float fv[8] = {f0.x, f0.y, f0.z, f0.w, f1.x, f1.y, f1.z, f1.w};
                ushort8 uh, ul;
                #pragma unroll
                for (int j = 0; j < 8; ++j) {
                    unsigned short rh = bf16_rne_bits(fv[j]);
                    float lo = fv[j] - bf16_bits_to_f32(rh);
                    uh[j] = rh;
                    ul[j] = bf16_rne_bits(lo);
                }
                vh = __builtin_bit_cast(bf16x8, uh);
                vl = __builtin_bit_cast(bf16x8, ul);
            } else {
                vh = *reinterpret_cast<const bf16x8*>(&hh[kg - EDIM]);
                vl = *reinterpret_cast<const bf16x8*>(&hl[kg - EDIM]);
            }
            *reinterpret_cast<bf16x8*>(&Ah[(ch * 64 + b) * 8]) = vh;
            *reinterpret_cast<bf16x8*>(&Al[(ch * 64 + b) * 8]) = vl;
        }
    }
    __syncthreads();

    // ---- MFMA: z = A * W (hi/lo split, 3 terms) ----
    const int lane  = tid & 63;
    const int w     = tid >> 6;
    const int mhalf = w & 1;          // rows 0-31 / 32-63
    const int nhalf = w >> 1;         // gates {0,1} / {2,3}
    const int l15   = lane & 15;
    const int q     = lane >> 4;

    f32x4 acc[2][2] = {};             // [mt][gate_local]

    const int col = bx * 16 + l15;
    const size_t kbase = (size_t)ks * KPER + q * 8;
    const __bf16* wh0 = Wt_hi + (size_t)((nhalf * 2 + 0) * HDIM + col) * KDIM + kbase;
    const __bf16* wl0 = Wt_lo + (size_t)((nhalf * 2 + 0) * HDIM + col) * KDIM + kbase;
    const __bf16* wh1 = Wt_hi + (size_t)((nhalf * 2 + 1) * HDIM + col) * KDIM + kbase;
    const __bf16* wl1 = Wt_lo + (size_t)((nhalf * 2 + 1) * HDIM + col) * KDIM + kbase;

    const int arow0 = mhalf * 32 + l15;       // mt=0 row
    #pragma unroll
    for (int kk = 0; kk < 12; ++kk) {
        const int chq = kk * 4 + q;
        bf16x8 ah0 = *reinterpret_cast<const bf16x8*>(&Ah[(chq * 64 + arow0) * 8]);
        bf16x8 ah1 = *reinterpret_cast<const bf16x8*>(&Ah[(chq * 64 + arow0 + 16) * 8]);
        bf16x8 al0 = *reinterpret_cast<const bf16x8*>(&Al[(chq * 64 + arow0) * 8]);
        bf16x8 al1 = *reinterpret_cast<const bf16x8*>(&Al[(chq * 64 + arow0 + 16) * 8]);
        bf16x8 bh0 = *reinterpret_cast<const bf16x8*>(&wh0[kk * 32]);
        bf16x8 bl0 = *reinterpret_cast<const bf16x8*>(&wl0[kk * 32]);
        bf16x8 bh1 = *reinterpret_cast<const bf16x8*>(&wh1[kk * 32]);
        bf16x8 bl1 = *reinterpret_cast<const bf16x8*>(&wl1[kk * 32]);

        acc[0][0] = __builtin_amdgcn_mfma_f32_16x16x32_bf16(ah0, bh0, acc[0][0], 0, 0, 0);
        acc[1][0] = __builtin_amdgcn_mfma_f32_16x16x32_bf16(ah1, bh0, acc[1][0], 0, 0, 0);
        acc[0][1] = __builtin_amdgcn_mfma_f32_16x16x32_bf16(ah0, bh1, acc[0][1], 0, 0, 0);
        acc[1][1] = __builtin_amdgcn_mfma_f32_16x16x32_bf16(ah1, bh1, acc[1][1], 0, 0, 0);
        acc[0][0] = __builtin_amdgcn_mfma_f32_16x16x32_bf16(ah0, bl0, acc[0][0], 0, 0, 0);
        acc[1][0] = __builtin_amdgcn_mfma_f32_16x16x32_bf16(ah1, bl0, acc[1][0], 0, 0, 0);
        acc[0][1] = __builtin_amdgcn_mfma_f32_16x16x32_bf16(ah0, bl1, acc[0][1], 0, 0, 0);
        acc[1][1] = __builtin_amdgcn_mfma_f32_16x16x32_bf16(ah1, bl1, acc[1][1], 0, 0, 0);
        acc[0][0] = __builtin_amdgcn_mfma_f32_16x16x32_bf16(al0, bh0, acc[0][0], 0, 0, 0);
        acc[1][0] = __builtin_amdgcn_mfma_f32_16x16x32_bf16(al1, bh0, acc[1][0], 0, 0, 0);
        acc[0][1] = __builtin_amdgcn_mfma_f32_16x16x32_bf16(al0, bh1, acc[0][1], 0, 0, 0);
        acc[1][1] = __builtin_amdgcn_mfma_f32_16x16x32_bf16(al1, bh1, acc[1][1], 0, 0, 0);
    }

    // ---- publish partials ----
    float* zp = zpart + (((size_t)ks * 64 + bx) * 64) * 64;
    #pragma unroll
    for (int mt = 0; mt < 2; ++mt)
        #pragma unroll
        for (int gl = 0; gl < 2; ++gl) {
            const int nc = (nhalf * 2 + gl) * 16 + l15;
            #pragma unroll
            for (int r = 0; r < 4; ++r) {
                const int row = mhalf * 32 + mt * 16 + q * 4 + r;
                zp[row * 64 + nc] = acc[mt][gl][r];
            }
        }
    __threadfence();
    if (tid == 0) {
        uint old = atomicAdd(&cnt[bx], 1u);
        winner_flag = (old == (uint)(4 * t + 3)) ? 1u : 0u;
    }
    __syncthreads();

    // ---- last finisher: reduce 4 partials, gates, h/c update ----
    if (winner_flag) {
        __threadfence();
        #pragma unroll
        for (int i = 0; i < 4; ++i) {
            const int p   = tid + 256 * i;    // 0..1023
            const int b   = p & 63;
            const int hcl = p >> 6;           // 0..15
            const int hc  = bx * 16 + hcl;
            float z[4];
            #pragma unroll
            for (int g = 0; g < 4; ++g) {
                float s = 0.0f;
                #pragma unroll
                for (int k2 = 0; k2 < KS; ++k2) {
                    const float* src = zpart +
                        (((size_t)k2 * 64 + bx) * 64 + b) * 64 + g * 16 + hcl;
                    s += __hip_atomic_load(src, __ATOMIC_RELAXED,
                                           __HIP_MEMORY_SCOPE_AGENT);
                }
                z[g] = s;
            }
            z[0] += bi[hc]; z[1] += bo[hc]; z[2] += bfp[hc]; z[3] += bm[hc];
            const float ig = 1.0f / (1.0f + expf(-z[0]));
            const float og = 1.0f / (1.0f + expf(-z[1]));
            const float fg = 1.0f / (1.0f + expf(-z[2]));
            const float mg = tanhf(z[3]);
            const float cv = fg * cbuf[b * HDIM + hc] + ig * mg;
            cbuf[b * HDIM + hc] = cv;
            const float hv = og * tanhf(cv);
            out[((size_t)b * T_STEPS + t) * HDIM + hc] = hv;
            unsigned short rh = bf16_rne_bits(hv);
            float lo = hv - bf16_bits_to_f32(rh);
            h_hi[b * HDIM + hc] = __builtin_bit_cast(__bf16, rh);
            h_lo[b * HDIM + hc] = __builtin_bit_cast(__bf16, bf16_rne_bits(lo));
        }
    }
}

// ================= fp32 fallback (small ws) =================
#define KT 128
#define LDS_PAD 130

__global__ __launch_bounds__(256) void zero_kernel(float* p, int n) {
    int i = blockIdx.x * 256 + threadIdx.x;
    if (i < n) p[i] = 0.0f;
}

__global__ __launch_bounds__(256) void gemm_step_f32(
    const float* __restrict__ x, const float* __restrict__ hbuf,
    const float* __restrict__ Wi, const float* __restrict__ Wo,
    const float* __restrict__ Wf, const float* __restrict__ Wm,
    float* __restrict__ z_part, int t)
{
    __shared__ float lds[BSZ * LDS_PAD];
    const int tid = threadIdx.x;
    const int n0  = blockIdx.x * 64;
    const int ks  = blockIdx.y;
    const int nl  = 4 * (tid & 15);
    const int b0  = 4 * (tid >> 4);
    const int g = n0 >> 10;
    const float* W = (g == 0) ? Wi : (g == 1) ? Wo : (g == 2) ? Wf : Wm;
    const int ncol = (n0 & 1023) + nl;
    float acc[4][4] = {};
    const float* xrow = x + (size_t)t * BSZ * EDIM;
    for (int kt = 0; kt < KPER; kt += KT) {
        const int kbase = ks * KPER + kt;
        #pragma unroll
        for (int i = 0; i < (BSZ * KT) / 256; ++i) {
            int idx = tid + 256 * i;
            int b = idx >> 7, kk = idx & (KT - 1);
            int kg = kbase + kk;
            lds[b * LDS_PAD + kk] = (kg < EDIM) ? xrow[b * EDIM + kg]
                                                : hbuf[b * HDIM + (kg - EDIM)];
        }
        __syncthreads();
        for (int kk = 0; kk < KT; kk += 2) {
            const int kg = kbase + kk;
            float4 w0 = *reinterpret_cast<const float4*>(&W[(size_t)kg * HDIM + ncol]);
            float4 w1 = *reinterpret_cast<const float4*>(&W[(size_t)(kg + 1) * HDIM + ncol]);
            #pragma unroll
            for (int j = 0; j < 4; ++j) {
                float2 a = *reinterpret_cast<const float2*>(&lds[(b0 + j) * LDS_PAD + kk]);
                acc[j][0] += a.x * w0.x; acc[j][1] += a.x * w0.y;
                acc[j][2] += a.x * w0.z; acc[j][3] += a.x * w0.w;
                acc[j][0] += a.y * w1.x; acc[j][1] += a.y * w1.y;
                acc[j][2] += a.y * w1.z; acc[j][3] += a.y * w1.w;
            }
        }
        __syncthreads();
    }
    #pragma unroll
    for (int j = 0; j < 4; ++j) {
        float4 v = make_float4(acc[j][0], acc[j][1], acc[j][2], acc[j][3]);
        *reinterpret_cast<float4*>(&z_part[((size_t)ks * BSZ + (b0 + j)) * N4 + n0 + nl]) = v;
    }
}

__global__ __launch_bounds__(256) void gates_step_f32(
    const float* __restrict__ z_part,
    const float* __restrict__ bi, const float* __restrict__ bo,
    const float* __restrict__ bf_, const float* __restrict__ bm,
    float* __restrict__ hbuf, float* __restrict__ cbuf,
    float* __restrict__ out, int t)
{
    const int idx = blockIdx.x * 256 + threadIdx.x;
    const int b = idx >> 10, hh = idx & 1023;
    float zi = bi[hh], zo = bo[hh], zf = bf_[hh], zm = bm[hh];
    #pragma unroll
    for (int s = 0; s < 4; ++s) {
        const float* zpp = z_part + ((size_t)s * BSZ + b) * N4;
        zi += zpp[hh]; zo += zpp[1024 + hh]; zf += zpp[2048 + hh]; zm += zpp[3072 + hh];
    }
    float ig = 1.0f / (1.0f + expf(-zi));
    float og = 1.0f / (1.0f + expf(-zo));
    float fg = 1.0f / (1.0f + expf(-zf));
    float mg = tanhf(zm);
    float cv = fg * cbuf[idx] + ig * mg;
    float hv = og * tanhf(cv);
    cbuf[idx] = cv; hbuf[idx] = hv;
    out[((size_t)b * T_STEPS + t) * HDIM + hh] = hv;
}

// ================= launch =================
extern "C" void kernel_launch(void* const* d_in, const int* in_sizes, int n_in,
                              void* d_out, int out_size, void* d_ws, size_t ws_size,
                              hipStream_t stream) {
    const float* x   = (const float*)d_in[0];
    const float* Wi  = (const float*)d_in[1];
    const float* bi  = (const float*)d_in[2];
    const float* Wo  = (const float*)d_in[3];
    const float* bo  = (const float*)d_in[4];
    const float* Wf  = (const float*)d_in[5];
    const float* bfp = (const float*)d_in[6];
    const float* Wm  = (const float*)d_in[7];
    const float* bm  = (const float*)d_in[8];
    float* out = (float*)d_out;

    // ws layout (bytes)
    const size_t SZ_WT   = (size_t)N4 * KDIM * 2;        // 12.58 MB each
    const size_t SZ_ZP   = (size_t)KS * 64 * 64 * 64 * 4; // 4 MB
    const size_t SZ_C    = (size_t)BSZ * HDIM * 4;
    const size_t SZ_H    = (size_t)BSZ * HDIM * 2;
    const size_t NEED = 2 * SZ_WT + SZ_ZP + SZ_C + 2 * SZ_H + 256;

    char* wsb = (char*)d_ws;
    if (ws_size >= NEED) {
        __bf16* Wt_hi = (__bf16*)wsb;
        __bf16* Wt_lo = (__bf16*)(wsb + SZ_WT);
        float*  zpart = (float*) (wsb + 2 * SZ_WT);
        float*  cbuf  = (float*) (wsb + 2 * SZ_WT + SZ_ZP);
        __bf16* h_hi  = (__bf16*)(wsb + 2 * SZ_WT + SZ_ZP + SZ_C);
        __bf16* h_lo  = (__bf16*)(wsb + 2 * SZ_WT + SZ_ZP + SZ_C + SZ_H);
        uint*   cnt   = (uint*)  (wsb + 2 * SZ_WT + SZ_ZP + SZ_C + 2 * SZ_H);

        init_state<<<dim3((BSZ * HDIM + 255) / 256), 256, 0, stream>>>(
            cbuf, h_hi, h_lo, cnt);
        prep_w<<<dim3(KDIM / 32, HDIM / 32, 4), 256, 0, stream>>>(
            Wi, Wo, Wf, Wm, Wt_hi, Wt_lo);

        for (int t = 0; t < T_STEPS; ++t) {
            step_kernel<<<dim3(64, KS), 256, 0, stream>>>(
                x, Wt_hi, Wt_lo, bi, bo, bfp, bm,
                h_hi, h_lo, cbuf, zpart, cnt, out, t);
        }
    } else {
        // fp32 fallback
        float* hbuf  = (float*)d_ws;
        float* cbuf  = hbuf + BSZ * HDIM;
        float* zpart = cbuf + BSZ * HDIM;
        zero_kernel<<<dim3((2 * BSZ * HDIM + 255) / 256), 256, 0, stream>>>(
            hbuf, 2 * BSZ * HDIM);
        for (int t = 0; t < T_STEPS; ++t) {
            gemm_step_f32<<<dim3(64, KS), 256, 0, stream>>>(
                x, hbuf, Wi, Wo, Wf, Wm, zpart, t);
            gates_step_f32<<<dim3((BSZ * HDIM) / 256), 256, 0, stream>>>(
                zpart, bi, bo, bfp, bm, hbuf, cbuf, out, t);
        }
    }
}